// Round 7
// baseline (163.616 us; speedup 1.0000x reference)
//
#include <hip/hip_runtime.h>
#include <hip/hip_bf16.h>

typedef __attribute__((ext_vector_type(8))) short bf16x8;
typedef __attribute__((ext_vector_type(4))) float f32x4;

#define B_ 8
#define S_ 1024
#define R_ 16384
#define H_ 128
#define D_ 256     // input dim = 2H
#define F_ 384     // inter dim

__device__ __forceinline__ unsigned short f2bf(float x) {
    unsigned int u = __float_as_uint(x);
    u += 0x7FFF + ((u >> 16) & 1);   // round-to-nearest-even
    return (unsigned short)(u >> 16);
}

__device__ __forceinline__ unsigned pack2bf(float a, float b) {
    float2 t; t.x = a; t.y = b;
    __hip_bfloat162 h = __float22bfloat162_rn(t);   // v_cvt_pk_bf16_f32
    return *reinterpret_cast<unsigned*>(&h);
}

// One fused prep kernel: span fp32->bf16, W1 transpose+cvt, W2 transpose+cvt.
__global__ __launch_bounds__(256) void k_prep(const float* __restrict__ span,
                                              const float* __restrict__ W1,
                                              const float* __restrict__ W2,
                                              unsigned short* __restrict__ spanbf,
                                              unsigned short* __restrict__ W1T,
                                              unsigned short* __restrict__ W2T) {
    const int bid = blockIdx.x;
    const int t = threadIdx.x;
    if (bid < 1024) {
        int i = bid * 256 + t;
        float4 v = reinterpret_cast<const float4*>(span)[i];
        ushort4 o;
        o.x = f2bf(v.x); o.y = f2bf(v.y); o.z = f2bf(v.z); o.w = f2bf(v.w);
        reinterpret_cast<ushort4*>(spanbf)[i] = o;
    } else if (bid < 1408) {
        int i = (bid - 1024) * 256 + t;       // W1T[f][d] = W1[d][f]
        int d = i & 255, f = i >> 8;
        W1T[i] = f2bf(W1[d * F_ + f]);
    } else {
        int i = (bid - 1408) * 256 + t;       // W2T[o][f] = W2[f][o]
        int o = i / F_, f = i - o * F_;
        W2T[i] = f2bf(W2[f * H_ + o]);
    }
}

// Persistent-4: grid 512, 512 threads (8 waves), each block = 4 tiles x 64 rows.
// LDS 80 KiB disjoint (R2 layout): sA [64][256] bf16 (32 KiB), sH [64][384] bf16
// (48 KiB), both XOR-swizzled byte^=((m&7)<<4).  2 barriers per tile:
//   barY (loop top): sA(t) staged ready; sH(t-1) reads complete
//   barX           : sH(t) written;      sA(t) L1-reads complete
// Cross-tile pipeline (T14): ids+gather(t+1) ISSUE at loop top (global latency
// hides under L1 MFMA); gather ds_write lands after barX (overlaps L2 MFMA).
// Layer 1: wave w owns f in [w*48,+48), W1 frags streamed from L2 in-loop.
// Layer 2: wave w owns o in [w*16,+16), W2 frags preloaded after epi1.
// Swapped mfma operands (W as A-operand): lane holds 4 consecutive f / o.
__global__ __launch_bounds__(512, 4) void k_main(
    const unsigned short* __restrict__ spanbf,
    const int* __restrict__ rel_ids,
    const unsigned short* __restrict__ W1T,
    const float* __restrict__ b1,
    const unsigned short* __restrict__ W2T,
    const float* __restrict__ b2,
    float* __restrict__ out)
{
    extern __shared__ char smem[];
    char* sA = smem;              // 32 KiB
    char* sH = smem + 32768;      // 48 KiB

    const int tid = threadIdx.x;
    const int blk = blockIdx.x;           // 0..511
    const int m0  = blk << 8;             // 256 rows per block (4 tiles of 64)
    const int b   = m0 >> 14;             // batch (64 blocks per batch)
    const int r0  = m0 & 16383;

    const int w  = tid >> 6;   // wave 0..7
    const int l  = tid & 63;
    const int lr = l & 15;
    const int lg = l >> 4;

    // ---------------- gather lane mapping ----------------
    const int gm = tid >> 3;              // 0..63 local row
    const int ge = tid & 7;               // eighth of the 512-B row
    const int gswz = (gm & 7) << 4;
    const int gbase = gm * 512 + ge * 64;
    const long spanbase = ((long)b << 17);           // b*1024*128 elements
    const int2* idp = reinterpret_cast<const int2*>(rel_ids) + (((long)b << 14) + r0);

    // persistent bias fragments
    const int fb0 = w * 48 + lg * 4;
    const float4 bias1_0 = *reinterpret_cast<const float4*>(b1 + fb0);
    const float4 bias1_1 = *reinterpret_cast<const float4*>(b1 + fb0 + 16);
    const float4 bias1_2 = *reinterpret_cast<const float4*>(b1 + fb0 + 32);
    const int ob = w * 16 + lg * 4;
    const float4 bias2 = *reinterpret_cast<const float4*>(b2 + ob);

    // ---------------- prologue: stage tile 0 ----------------
    {
        const int2 ids = idp[gm];
        const int idx = (ge < 4) ? ids.x : ids.y;
        const uint4* src = reinterpret_cast<const uint4*>(
            spanbf + spanbase + ((long)idx << 7) + ((ge & 3) << 5));
        #pragma unroll
        for (int j = 0; j < 4; ++j) {
            uint4 v = src[j];
            *reinterpret_cast<uint4*>(sA + ((gbase + j * 16) ^ gswz)) = v;
        }
    }

    // ================= persistent tile loop =================
    #pragma unroll 1
    for (int t = 0; t < 4; ++t) {
        __syncthreads();                  // barY: sA(t) ready; sH reads(t-1) done

        // issue next tile's gather loads NOW (latency hides under L1 phase)
        uint4 g0, g1, g2, g3;
        if (t < 3) {
            const int2 ids2 = idp[(t + 1) * 64 + gm];
            const int idx = (ge < 4) ? ids2.x : ids2.y;
            const uint4* src = reinterpret_cast<const uint4*>(
                spanbf + spanbase + ((long)idx << 7) + ((ge & 3) << 5));
            g0 = src[0]; g1 = src[1]; g2 = src[2]; g3 = src[3];
        }

        // ---------------- layer 1: h^T tiles = W1slice @ A^T (R2 body) ----
        f32x4 acc[3][4];
        #pragma unroll
        for (int ft = 0; ft < 3; ++ft)
            #pragma unroll
            for (int mt = 0; mt < 4; ++mt) acc[ft][mt] = {0.f, 0.f, 0.f, 0.f};

        #pragma unroll 1
        for (int kp = 0; kp < 4; ++kp) {  // k-pairs: kt = kp*2 + k2
            bf16x8 Af[4][2];
            #pragma unroll
            for (int mt = 0; mt < 4; ++mt) {
                const int m = mt * 16 + lr;
                const int swz = (m & 7) << 4;
                #pragma unroll
                for (int k2 = 0; k2 < 2; ++k2) {
                    const int kt = kp * 2 + k2;
                    Af[mt][k2] = *reinterpret_cast<const bf16x8*>(
                        sA + ((m * 512 + kt * 64 + lg * 16) ^ swz));
                }
            }
            #pragma unroll
            for (int ft = 0; ft < 3; ++ft) {
                const unsigned short* wr = W1T + (unsigned)(w * 48 + ft * 16 + lr) * 256 + lg * 8;
                #pragma unroll
                for (int k2 = 0; k2 < 2; ++k2) {
                    const int kt = kp * 2 + k2;
                    bf16x8 Wf = *reinterpret_cast<const bf16x8*>(wr + kt * 32);
                    #pragma unroll
                    for (int mt = 0; mt < 4; ++mt)
                        acc[ft][mt] = __builtin_amdgcn_mfma_f32_16x16x32_bf16(
                            Wf, Af[mt][k2], acc[ft][mt], 0, 0, 0);
                }
            }
        }

        // ---------------- epilogue 1: bias + relu -> sH (R2 body) ----------
        #pragma unroll
        for (int ft = 0; ft < 3; ++ft) {
            const int fb = w * 48 + ft * 16 + lg * 4;
            const float4 bias = (ft == 0) ? bias1_0 : (ft == 1) ? bias1_1 : bias1_2;
            #pragma unroll
            for (int mt = 0; mt < 4; ++mt) {
                float v0 = fmaxf(acc[ft][mt][0] + bias.x, 0.0f);
                float v1 = fmaxf(acc[ft][mt][1] + bias.y, 0.0f);
                float v2 = fmaxf(acc[ft][mt][2] + bias.z, 0.0f);
                float v3 = fmaxf(acc[ft][mt][3] + bias.w, 0.0f);
                uint2 p;
                p.x = pack2bf(v0, v1);
                p.y = pack2bf(v2, v3);
                const int m = mt * 16 + lr;
                *reinterpret_cast<uint2*>(
                    sH + ((m * 768 + fb * 2) ^ ((m & 7) << 4))) = p;
            }
        }

        // preload W2 fragments (acc is dead now; issued before barX, used after)
        bf16x8 W2f[12];
        {
            const unsigned short* w2p = W2T + (unsigned)(w * 16 + lr) * 384 + lg * 8;
            #pragma unroll
            for (int kt = 0; kt < 12; ++kt)
                W2f[kt] = *reinterpret_cast<const bf16x8*>(w2p + kt * 32);
        }

        __syncthreads();                  // barX: sH ready; all sA L1-reads done

        // stage next tile into sA (overlaps layer-2 MFMA)
        if (t < 3) {
            *reinterpret_cast<uint4*>(sA + ((gbase +  0) ^ gswz)) = g0;
            *reinterpret_cast<uint4*>(sA + ((gbase + 16) ^ gswz)) = g1;
            *reinterpret_cast<uint4*>(sA + ((gbase + 32) ^ gswz)) = g2;
            *reinterpret_cast<uint4*>(sA + ((gbase + 48) ^ gswz)) = g3;
        }

        // ---------------- layer 2: out^T tiles = W2slice @ h^T (R2 body) ----
        f32x4 acc2[4];
        #pragma unroll
        for (int mt = 0; mt < 4; ++mt) acc2[mt] = {0.f, 0.f, 0.f, 0.f};

        #pragma unroll
        for (int kt = 0; kt < 12; ++kt) {
            #pragma unroll
            for (int mt = 0; mt < 4; ++mt) {
                const int m = mt * 16 + lr;
                bf16x8 Hf = *reinterpret_cast<const bf16x8*>(
                    sH + ((m * 768 + kt * 64 + lg * 16) ^ ((m & 7) << 4)));
                acc2[mt] = __builtin_amdgcn_mfma_f32_16x16x32_bf16(
                    W2f[kt], Hf, acc2[mt], 0, 0, 0);
            }
        }

        // epilogue 2: bias + direct float4 global stores
        float* outp = out + ((long)(m0 + t * 64)) * 128;
        #pragma unroll
        for (int mt = 0; mt < 4; ++mt) {
            const int m = mt * 16 + lr;
            float4 v;
            v.x = acc2[mt][0] + bias2.x;
            v.y = acc2[mt][1] + bias2.y;
            v.z = acc2[mt][2] + bias2.z;
            v.w = acc2[mt][3] + bias2.w;
            *reinterpret_cast<float4*>(outp + m * 128 + ob) = v;
        }
    }
}

extern "C" void kernel_launch(void* const* d_in, const int* in_sizes, int n_in,
                              void* d_out, int out_size, void* d_ws, size_t ws_size,
                              hipStream_t stream) {
    const float* span = (const float*)d_in[0];
    const int*   rel  = (const int*)d_in[1];
    const float* W1   = (const float*)d_in[2];
    const float* b1   = (const float*)d_in[3];
    const float* W2   = (const float*)d_in[4];
    const float* b2   = (const float*)d_in[5];
    float* out = (float*)d_out;

    unsigned short* spanbf = (unsigned short*)d_ws;        // 2 MiB
    unsigned short* W1T = spanbf + B_ * S_ * H_;           // 192 KiB
    unsigned short* W2T = W1T + D_ * F_;                   // 96 KiB

    k_prep<<<1600, 256, 0, stream>>>(span, W1, W2, spanbf, W1T, W2T);
    k_main<<<512, 512, 81920, stream>>>(spanbf, rel, W1T, b1, W2T, b2, out);
}

// Round 8
// 159.768 us; speedup vs baseline: 1.0241x; 1.0241x over previous
//
#include <hip/hip_runtime.h>
#include <hip/hip_bf16.h>

typedef __attribute__((ext_vector_type(8))) short bf16x8;
typedef __attribute__((ext_vector_type(4))) float f32x4;

#define B_ 8
#define S_ 1024
#define R_ 16384
#define H_ 128
#define D_ 256     // input dim = 2H
#define F_ 384     // inter dim

__device__ __forceinline__ unsigned short f2bf(float x) {
    unsigned int u = __float_as_uint(x);
    u += 0x7FFF + ((u >> 16) & 1);   // round-to-nearest-even
    return (unsigned short)(u >> 16);
}

__device__ __forceinline__ unsigned pack2bf(float a, float b) {
    float2 t; t.x = a; t.y = b;
    __hip_bfloat162 h = __float22bfloat162_rn(t);   // v_cvt_pk_bf16_f32
    return *reinterpret_cast<unsigned*>(&h);
}

// global -> LDS direct DMA, 16 B per lane, zero VGPR round-trip.
// LDS dest is wave-uniform base + lane*16 (HW rule); global src is per-lane.
__device__ __forceinline__ void glld16(const unsigned short* g, char* l) {
    __builtin_amdgcn_global_load_lds(
        (__attribute__((address_space(1))) void*)(g),
        (__attribute__((address_space(3))) void*)(l),
        16, 0, 0);
}

// One fused prep kernel: span fp32->bf16, W1 transpose+cvt, W2 transpose+cvt.
__global__ __launch_bounds__(256) void k_prep(const float* __restrict__ span,
                                              const float* __restrict__ W1,
                                              const float* __restrict__ W2,
                                              unsigned short* __restrict__ spanbf,
                                              unsigned short* __restrict__ W1T,
                                              unsigned short* __restrict__ W2T) {
    const int bid = blockIdx.x;
    const int t = threadIdx.x;
    if (bid < 1024) {
        int i = bid * 256 + t;
        float4 v = reinterpret_cast<const float4*>(span)[i];
        ushort4 o;
        o.x = f2bf(v.x); o.y = f2bf(v.y); o.z = f2bf(v.z); o.w = f2bf(v.w);
        reinterpret_cast<ushort4*>(spanbf)[i] = o;
    } else if (bid < 1408) {
        int i = (bid - 1024) * 256 + t;       // W1T[f][d] = W1[d][f]
        int d = i & 255, f = i >> 8;
        W1T[i] = f2bf(W1[d * F_ + f]);
    } else {
        int i = (bid - 1408) * 256 + t;       // W2T[o][f] = W2[f][o]
        int o = i / F_, f = i - o * F_;
        W2T[i] = f2bf(W2[f * H_ + o]);
    }
}

// Persistent-4 with DMA staging: grid 512, 512 threads (8 waves), 4 tiles x 64
// rows per block. LDS 80 KiB (R2 layout): sA [64][256] bf16 (32 KiB) + sH
// [64][384] bf16 (48 KiB), both XOR-swizzled byte^=((m&7)<<4).
// Per tile: barY -> L1(R2 body) -> epi1 -> W2 preload -> barX ->
//           global_load_lds stage(t+1) (lands under L2 phase) -> L2(R2 body)
//           -> direct float4 stores.
// Staging uses PRE-SWIZZLED global source: lane l, chunk j owns LDS bytes
// [w*4096 + j*1024 + l*16, +16) = row m = w*8+j*2+(l>>5), swizzled col
// cs = (l&31)*16, real col c = cs ^ ((m&7)<<4); src = span row (c<256 ?
// head : tail) + (c&255). Zero VGPRs held in flight -> no spill.
__global__ __launch_bounds__(512, 4) void k_main(
    const unsigned short* __restrict__ spanbf,
    const int* __restrict__ rel_ids,
    const unsigned short* __restrict__ W1T,
    const float* __restrict__ b1,
    const unsigned short* __restrict__ W2T,
    const float* __restrict__ b2,
    float* __restrict__ out)
{
    extern __shared__ char smem[];
    char* sA = smem;              // 32 KiB
    char* sH = smem + 32768;      // 48 KiB

    const int tid = threadIdx.x;
    const int blk = blockIdx.x;           // 0..511
    const int m0  = blk << 8;             // 256 rows per block (4 tiles of 64)
    const int b   = m0 >> 14;             // batch (64 blocks per batch)
    const int r0  = m0 & 16383;

    const int w  = tid >> 6;   // wave 0..7
    const int l  = tid & 63;
    const int lr = l & 15;
    const int lg = l >> 4;

    const unsigned short* spanb = spanbf + (((long)b) << 17);
    const int2* idp = reinterpret_cast<const int2*>(rel_ids) + (((long)b << 14) + r0);

    // persistent bias fragments
    const int fb0 = w * 48 + lg * 4;
    const float4 bias1_0 = *reinterpret_cast<const float4*>(b1 + fb0);
    const float4 bias1_1 = *reinterpret_cast<const float4*>(b1 + fb0 + 16);
    const float4 bias1_2 = *reinterpret_cast<const float4*>(b1 + fb0 + 32);
    const int ob = w * 16 + lg * 4;
    const float4 bias2 = *reinterpret_cast<const float4*>(b2 + ob);

    // ---------- DMA stage of tile t into sA (pre-swizzled source) ----------
    const int cs = (l & 31) << 4;                  // swizzled col byte
    auto stage_tile = [&](int t) {
        #pragma unroll
        for (int j = 0; j < 4; ++j) {
            const int m = w * 8 + j * 2 + (l >> 5);         // row in tile
            const int c = cs ^ ((m & 7) << 4);              // real col byte
            const int2 ids = idp[t * 64 + m];
            const int idx = (c < 256) ? ids.x : ids.y;
            const unsigned short* src = spanb + ((long)idx << 7) + ((c & 255) >> 1);
            glld16(src, sA + w * 4096 + j * 1024);
        }
    };

    // prologue: stage tile 0
    stage_tile(0);

    // ================= persistent tile loop =================
    #pragma unroll 1
    for (int t = 0; t < 4; ++t) {
        __syncthreads();                  // barY: sA(t) DMA'd (vmcnt drained); sH(t-1) reads done

        // ---------------- layer 1: h^T tiles = W1slice @ A^T (R2 body) ----
        f32x4 acc[3][4];
        #pragma unroll
        for (int ft = 0; ft < 3; ++ft)
            #pragma unroll
            for (int mt = 0; mt < 4; ++mt) acc[ft][mt] = {0.f, 0.f, 0.f, 0.f};

        #pragma unroll 1
        for (int kp = 0; kp < 4; ++kp) {  // k-pairs: kt = kp*2 + k2
            bf16x8 Af[4][2];
            #pragma unroll
            for (int mt = 0; mt < 4; ++mt) {
                const int m = mt * 16 + lr;
                const int swz = (m & 7) << 4;
                #pragma unroll
                for (int k2 = 0; k2 < 2; ++k2) {
                    const int kt = kp * 2 + k2;
                    Af[mt][k2] = *reinterpret_cast<const bf16x8*>(
                        sA + ((m * 512 + kt * 64 + lg * 16) ^ swz));
                }
            }
            #pragma unroll
            for (int ft = 0; ft < 3; ++ft) {
                const unsigned short* wr = W1T + (unsigned)(w * 48 + ft * 16 + lr) * 256 + lg * 8;
                #pragma unroll
                for (int k2 = 0; k2 < 2; ++k2) {
                    const int kt = kp * 2 + k2;
                    bf16x8 Wf = *reinterpret_cast<const bf16x8*>(wr + kt * 32);
                    #pragma unroll
                    for (int mt = 0; mt < 4; ++mt)
                        acc[ft][mt] = __builtin_amdgcn_mfma_f32_16x16x32_bf16(
                            Wf, Af[mt][k2], acc[ft][mt], 0, 0, 0);
                }
            }
        }

        // ---------------- epilogue 1: bias + relu -> sH (R2 body) ----------
        #pragma unroll
        for (int ft = 0; ft < 3; ++ft) {
            const int fb = w * 48 + ft * 16 + lg * 4;
            const float4 bias = (ft == 0) ? bias1_0 : (ft == 1) ? bias1_1 : bias1_2;
            #pragma unroll
            for (int mt = 0; mt < 4; ++mt) {
                float v0 = fmaxf(acc[ft][mt][0] + bias.x, 0.0f);
                float v1 = fmaxf(acc[ft][mt][1] + bias.y, 0.0f);
                float v2 = fmaxf(acc[ft][mt][2] + bias.z, 0.0f);
                float v3 = fmaxf(acc[ft][mt][3] + bias.w, 0.0f);
                uint2 p;
                p.x = pack2bf(v0, v1);
                p.y = pack2bf(v2, v3);
                const int m = mt * 16 + lr;
                *reinterpret_cast<uint2*>(
                    sH + ((m * 768 + fb * 2) ^ ((m & 7) << 4))) = p;
            }
        }

        // preload W2 fragments (acc dead; 48 VGPR across one barrier, as in R2)
        bf16x8 W2f[12];
        {
            const unsigned short* w2p = W2T + (unsigned)(w * 16 + lr) * 384 + lg * 8;
            #pragma unroll
            for (int kt = 0; kt < 12; ++kt)
                W2f[kt] = *reinterpret_cast<const bf16x8*>(w2p + kt * 32);
        }

        __syncthreads();                  // barX: sH ready; all sA L1-reads done

        // stage next tile via DMA — writes land during the L2 MFMA phase,
        // completion enforced by the vmcnt(0) at next loop-top barY.
        if (t < 3) stage_tile(t + 1);

        // ---------------- layer 2: out^T tiles = W2slice @ h^T (R2 body) ----
        f32x4 acc2[4];
        #pragma unroll
        for (int mt = 0; mt < 4; ++mt) acc2[mt] = {0.f, 0.f, 0.f, 0.f};

        #pragma unroll
        for (int kt = 0; kt < 12; ++kt) {
            #pragma unroll
            for (int mt = 0; mt < 4; ++mt) {
                const int m = mt * 16 + lr;
                bf16x8 Hf = *reinterpret_cast<const bf16x8*>(
                    sH + ((m * 768 + kt * 64 + lg * 16) ^ ((m & 7) << 4)));
                acc2[mt] = __builtin_amdgcn_mfma_f32_16x16x32_bf16(
                    W2f[kt], Hf, acc2[mt], 0, 0, 0);
            }
        }

        // epilogue 2: bias + direct float4 global stores
        float* outp = out + ((long)(m0 + t * 64)) * 128;
        #pragma unroll
        for (int mt = 0; mt < 4; ++mt) {
            const int m = mt * 16 + lr;
            float4 v;
            v.x = acc2[mt][0] + bias2.x;
            v.y = acc2[mt][1] + bias2.y;
            v.z = acc2[mt][2] + bias2.z;
            v.w = acc2[mt][3] + bias2.w;
            *reinterpret_cast<float4*>(outp + m * 128 + ob) = v;
        }
    }
}

extern "C" void kernel_launch(void* const* d_in, const int* in_sizes, int n_in,
                              void* d_out, int out_size, void* d_ws, size_t ws_size,
                              hipStream_t stream) {
    const float* span = (const float*)d_in[0];
    const int*   rel  = (const int*)d_in[1];
    const float* W1   = (const float*)d_in[2];
    const float* b1   = (const float*)d_in[3];
    const float* W2   = (const float*)d_in[4];
    const float* b2   = (const float*)d_in[5];
    float* out = (float*)d_out;

    unsigned short* spanbf = (unsigned short*)d_ws;        // 2 MiB
    unsigned short* W1T = spanbf + B_ * S_ * H_;           // 192 KiB
    unsigned short* W2T = W1T + D_ * F_;                   // 96 KiB

    k_prep<<<1600, 256, 0, stream>>>(span, W1, W2, spanbf, W1T, W2T);
    k_main<<<512, 512, 81920, stream>>>(spanbf, rel, W1T, b1, W2T, b2, out);
}

// Round 9
// 97.122 us; speedup vs baseline: 1.6846x; 1.6450x over previous
//
#include <hip/hip_runtime.h>
#include <hip/hip_bf16.h>

typedef __attribute__((ext_vector_type(8))) short bf16x8;
typedef __attribute__((ext_vector_type(16))) float f32x16;

#define B_ 8
#define S_ 1024
#define R_ 16384
#define H_ 128
#define D_ 256     // input dim = 2H
#define F_ 384     // inter dim

__device__ __forceinline__ unsigned short f2bf(float x) {
    unsigned int u = __float_as_uint(x);
    u += 0x7FFF + ((u >> 16) & 1);   // round-to-nearest-even
    return (unsigned short)(u >> 16);
}

__device__ __forceinline__ unsigned pack2bf(float a, float b) {
    float2 t; t.x = a; t.y = b;
    __hip_bfloat162 h = __float22bfloat162_rn(t);   // v_cvt_pk_bf16_f32
    return *reinterpret_cast<unsigned*>(&h);
}

// One fused prep kernel: span fp32->bf16, W1 transpose+cvt, W2 transpose+cvt.
__global__ __launch_bounds__(256) void k_prep(const float* __restrict__ span,
                                              const float* __restrict__ W1,
                                              const float* __restrict__ W2,
                                              unsigned short* __restrict__ spanbf,
                                              unsigned short* __restrict__ W1T,
                                              unsigned short* __restrict__ W2T) {
    const int bid = blockIdx.x;
    const int t = threadIdx.x;
    if (bid < 1024) {
        int i = bid * 256 + t;
        float4 v = reinterpret_cast<const float4*>(span)[i];
        ushort4 o;
        o.x = f2bf(v.x); o.y = f2bf(v.y); o.z = f2bf(v.z); o.w = f2bf(v.w);
        reinterpret_cast<ushort4*>(spanbf)[i] = o;
    } else if (bid < 1408) {
        int i = (bid - 1024) * 256 + t;       // W1T[f][d] = W1[d][f]
        int d = i & 255, f = i >> 8;
        W1T[i] = f2bf(W1[d * F_ + f]);
    } else {
        int i = (bid - 1408) * 256 + t;       // W2T[o][f] = W2[f][o]
        int o = i / F_, f = i - o * F_;
        W2T[i] = f2bf(W2[f * H_ + o]);
    }
}

// 64 rows/block, 4 waves (256 threads), 32x32x16 MFMA (half the LDS bytes/FLOP
// and half the MFMA instructions vs 16x16x32). LDS 48 KiB OVERLAPPED:
//   phase A: sA = buf[0..32K)  [64][256] bf16, stride 512 B, swz byte^=((m&7)<<4)
//   phase H: sH = buf[0..48K)  [64][384] bf16, stride 768 B, same swz
// -> 3 blocks/CU (12 waves). 3 barriers: stage|L1reads ; L1reads|sHwrites ;
// sHwrites|L2reads. Direct float4 out stores (ideal 64 MB write traffic).
// Layer 1: wave w owns f in [w*96,+96) as 3 f-tiles of 32; all 64 rows (2 m-tiles).
// Layer 2: wave w owns o in [w*32,+32); 2 m-tiles.
// Swapped operands mfma(Wf, Af): 32x32 D layout col(=m)=lane&31,
// row(=f/o offset)=(reg&3)+8*(reg>>2)+4*(lane>>5).
// A/B frag: lane holds 8 contiguous k at k=(lane>>5)*8, row/col = lane&31.
__global__ __launch_bounds__(256, 3) void k_main(
    const unsigned short* __restrict__ spanbf,
    const int* __restrict__ rel_ids,
    const unsigned short* __restrict__ W1T,
    const float* __restrict__ b1,
    const unsigned short* __restrict__ W2T,
    const float* __restrict__ b2,
    float* __restrict__ out)
{
    extern __shared__ char smem[];
    char* sA = smem;              // [64][256] bf16 (32 KiB), dies after L1 k-loop
    char* sH = smem;              // [64][384] bf16 (48 KiB), lives after bar2

    const int tid = threadIdx.x;
    const int blk = blockIdx.x;           // 0..2047
    const int m0  = blk << 6;             // first global row
    const int b   = m0 >> 14;             // batch
    const int r0  = m0 & 16383;

    const int w  = tid >> 6;   // wave 0..3
    const int l  = tid & 63;
    const int a  = l & 31;     // row/col within 32-tile
    const int hi = l >> 5;     // k-half selector

    const unsigned short* spanb = spanbf + ((long)b << 17);
    const int2* idp = reinterpret_cast<const int2*>(rel_ids) + (((long)b << 14) + r0);

    // ---------------- stage A: gathered rel_reps (bf16), 4 thr/row ----------
    {
        const int gm = tid >> 2;          // 0..63 local row
        const int e  = tid & 3;           // quarter of the 512-B row
        const int2 ids = idp[gm];
        const int idx = (e < 2) ? ids.x : ids.y;
        const unsigned short* src = spanb + ((long)idx << 7) + ((e & 1) << 6);
        const int base = gm * 512 + e * 128;
        const int swz = (gm & 7) << 4;
        #pragma unroll
        for (int j = 0; j < 8; ++j) {
            uint4 v = reinterpret_cast<const uint4*>(src)[j];
            *reinterpret_cast<uint4*>(sA + ((base + j * 16) ^ swz)) = v;
        }
    }
    __syncthreads();                      // bar1: sA ready

    // ---------------- layer 1: h^T tiles = W1slice @ A^T (32x32x16) --------
    const unsigned short* w1p = W1T + (unsigned)(w * 96 + a) * 256 + hi * 8;

    f32x16 acc0_0 = {0}, acc0_1 = {0}, acc1_0 = {0}, acc1_1 = {0}, acc2_0 = {0}, acc2_1 = {0};

    #pragma unroll
    for (int kt = 0; kt < 16; ++kt) {     // k = kt*16 + hi*8 .. +8
        bf16x8 Af0, Af1;
        {
            const int mA = a;                         // m-tile 0
            Af0 = *reinterpret_cast<const bf16x8*>(
                sA + mA * 512 + ((kt * 32 + hi * 16) ^ ((mA & 7) << 4)));
            const int mB = 32 + a;                    // m-tile 1
            Af1 = *reinterpret_cast<const bf16x8*>(
                sA + mB * 512 + ((kt * 32 + hi * 16) ^ ((mB & 7) << 4)));
        }
        bf16x8 Wf0 = *reinterpret_cast<const bf16x8*>(w1p + kt * 16);
        bf16x8 Wf1 = *reinterpret_cast<const bf16x8*>(w1p + 8192 + kt * 16);
        bf16x8 Wf2 = *reinterpret_cast<const bf16x8*>(w1p + 16384 + kt * 16);
        acc0_0 = __builtin_amdgcn_mfma_f32_32x32x16_bf16(Wf0, Af0, acc0_0, 0, 0, 0);
        acc0_1 = __builtin_amdgcn_mfma_f32_32x32x16_bf16(Wf0, Af1, acc0_1, 0, 0, 0);
        acc1_0 = __builtin_amdgcn_mfma_f32_32x32x16_bf16(Wf1, Af0, acc1_0, 0, 0, 0);
        acc1_1 = __builtin_amdgcn_mfma_f32_32x32x16_bf16(Wf1, Af1, acc1_1, 0, 0, 0);
        acc2_0 = __builtin_amdgcn_mfma_f32_32x32x16_bf16(Wf2, Af0, acc2_0, 0, 0, 0);
        acc2_1 = __builtin_amdgcn_mfma_f32_32x32x16_bf16(Wf2, Af1, acc2_1, 0, 0, 0);
    }

    __syncthreads();                      // bar2: all sA reads complete

    // ---------------- epilogue 1: bias + relu -> sH (b64 packed) -----------
    // D: col m = a (+32 for m-tile 1), rows f_off = (r&3)+8*(r>>2)+4*hi.
    #pragma unroll
    for (int ft = 0; ft < 3; ++ft) {
        const f32x16& A0 = (ft == 0) ? acc0_0 : (ft == 1) ? acc1_0 : acc2_0;
        const f32x16& A1 = (ft == 0) ? acc0_1 : (ft == 1) ? acc1_1 : acc2_1;
        #pragma unroll
        for (int q = 0; q < 4; ++q) {
            const int f0 = w * 96 + ft * 32 + 8 * q + 4 * hi;   // 4 consecutive f
            const float4 bias = *reinterpret_cast<const float4*>(b1 + f0);
            {   // m-tile 0
                const int m = a;
                uint2 p;
                p.x = pack2bf(fmaxf(A0[4*q+0] + bias.x, 0.f), fmaxf(A0[4*q+1] + bias.y, 0.f));
                p.y = pack2bf(fmaxf(A0[4*q+2] + bias.z, 0.f), fmaxf(A0[4*q+3] + bias.w, 0.f));
                *reinterpret_cast<uint2*>(sH + m * 768 + ((f0 * 2) ^ ((m & 7) << 4))) = p;
            }
            {   // m-tile 1
                const int m = 32 + a;
                uint2 p;
                p.x = pack2bf(fmaxf(A1[4*q+0] + bias.x, 0.f), fmaxf(A1[4*q+1] + bias.y, 0.f));
                p.y = pack2bf(fmaxf(A1[4*q+2] + bias.z, 0.f), fmaxf(A1[4*q+3] + bias.w, 0.f));
                *reinterpret_cast<uint2*>(sH + m * 768 + ((f0 * 2) ^ ((m & 7) << 4))) = p;
            }
        }
    }

    __syncthreads();                      // bar3: sH ready

    // ---------------- layer 2: out^T tiles = W2slice @ h^T (32x32x16) ------
    const unsigned short* w2p = W2T + (unsigned)(w * 32 + a) * 384 + hi * 8;

    f32x16 o_0 = {0}, o_1 = {0};
    #pragma unroll
    for (int kt = 0; kt < 24; ++kt) {     // k(=f) = kt*16 + hi*8 .. +8
        bf16x8 Wf = *reinterpret_cast<const bf16x8*>(w2p + kt * 16);
        {
            const int m = a;
            bf16x8 Hf = *reinterpret_cast<const bf16x8*>(
                sH + m * 768 + ((kt * 32 + hi * 16) ^ ((m & 7) << 4)));
            o_0 = __builtin_amdgcn_mfma_f32_32x32x16_bf16(Wf, Hf, o_0, 0, 0, 0);
        }
        {
            const int m = 32 + a;
            bf16x8 Hf = *reinterpret_cast<const bf16x8*>(
                sH + m * 768 + ((kt * 32 + hi * 16) ^ ((m & 7) << 4)));
            o_1 = __builtin_amdgcn_mfma_f32_32x32x16_bf16(Wf, Hf, o_1, 0, 0, 0);
        }
    }

    // ---------------- epilogue 2: bias + direct float4 stores ---------------
    float* outp = out + (long)m0 * 128;
    #pragma unroll
    for (int q = 0; q < 4; ++q) {
        const int o0 = w * 32 + 8 * q + 4 * hi;      // 4 consecutive o
        const float4 bias = *reinterpret_cast<const float4*>(b2 + o0);
        {
            const int m = a;
            float4 v;
            v.x = o_0[4*q+0] + bias.x;
            v.y = o_0[4*q+1] + bias.y;
            v.z = o_0[4*q+2] + bias.z;
            v.w = o_0[4*q+3] + bias.w;
            *reinterpret_cast<float4*>(outp + m * 128 + o0) = v;
        }
        {
            const int m = 32 + a;
            float4 v;
            v.x = o_1[4*q+0] + bias.x;
            v.y = o_1[4*q+1] + bias.y;
            v.z = o_1[4*q+2] + bias.z;
            v.w = o_1[4*q+3] + bias.w;
            *reinterpret_cast<float4*>(outp + m * 128 + o0) = v;
        }
    }
}

extern "C" void kernel_launch(void* const* d_in, const int* in_sizes, int n_in,
                              void* d_out, int out_size, void* d_ws, size_t ws_size,
                              hipStream_t stream) {
    const float* span = (const float*)d_in[0];
    const int*   rel  = (const int*)d_in[1];
    const float* W1   = (const float*)d_in[2];
    const float* b1   = (const float*)d_in[3];
    const float* W2   = (const float*)d_in[4];
    const float* b2   = (const float*)d_in[5];
    float* out = (float*)d_out;

    unsigned short* spanbf = (unsigned short*)d_ws;        // 2 MiB
    unsigned short* W1T = spanbf + B_ * S_ * H_;           // 192 KiB
    unsigned short* W2T = W1T + D_ * F_;                   // 96 KiB

    k_prep<<<1600, 256, 0, stream>>>(span, W1, W2, spanbf, W1T, W2T);
    k_main<<<(B_ * R_) / 64, 256, 49152, stream>>>(spanbf, rel, W1T, b1, W2T, b2, out);
}